// Round 11
// baseline (420.995 us; speedup 1.0000x reference)
//
#include <hip/hip_runtime.h>
#include <hip/hip_bf16.h>

// PAM (position attention): B=8, C=512, mid=64, N=64*64=4096.
// Round 11: revert to r7's proven homogeneous region skeleton; fix the
// geometry instead: I_TILE=64, FULL c=512 per block (kills the ch-split that
// duplicated all QK/exp/P-store work), c_strip=64/wave (each 16B P-read feeds
// 4 MFMAs instead of 2). 512 blocks = 8 batch x 64 i-tiles, 8 waves.
// Region t: {V(t+1) prefetch, QK(t+1) fp16 MFMA, K(t+2) prefetch,
//            exp2+cvt_pk+P-store(t+1)->buf^1, PV(t) from buf} -> lgkm barrier.
// r10 post-mortem: producer/consumer ring raced (absmax ~2^63 = 1/garbage-lsum);
// reverted per m152 (new sync structures need race screening).

#define BB 8
#define CC 512
#define MM 64
#define NN 4096
#define LOG2E 1.4426950408889634f

typedef __attribute__((ext_vector_type(8))) short bf16x8;
typedef __attribute__((ext_vector_type(8))) _Float16 f16x8;
typedef __attribute__((ext_vector_type(4))) float f32x4;

__device__ unsigned g_kmax[BB];  // per-batch max ||k||^2 (uint-ordered f32)

__device__ __forceinline__ unsigned short f2bf(float f) {
  union { float f; unsigned u; } v; v.f = f;
  unsigned r = v.u + 0x7fffu + ((v.u >> 16) & 1u);  // RNE
  return (unsigned short)(r >> 16);
}
__device__ __forceinline__ float bf2f(unsigned short h) {
  union { unsigned u; float f; } v; v.u = ((unsigned)h) << 16;
  return v.f;
}
__device__ __forceinline__ unsigned short f2h(float f) {
  union { _Float16 h; unsigned short u; } v; v.h = (_Float16)f;
  return v.u;
}

// ------------- kernel 0: weight pre-conversion + g_kmax init -------------
__global__ __launch_bounds__(256) void k_wconv(
    const float* __restrict__ wq, const float* __restrict__ wk,
    const float* __restrict__ wv,
    unsigned short* __restrict__ wqhi, unsigned short* __restrict__ wqlo,
    unsigned short* __restrict__ wkhi, unsigned short* __restrict__ wklo,
    unsigned short* __restrict__ wvbf) {
  const int tid = blockIdx.x * 256 + threadIdx.x;
  if (tid < BB) g_kmax[tid] = 0u;
  if (tid < MM * CC) {
    float v = wq[tid];
    unsigned short h = f2bf(v);
    wqhi[tid] = h; wqlo[tid] = f2bf(v - bf2f(h));
    v = wk[tid]; h = f2bf(v);
    wkhi[tid] = h; wklo[tid] = f2bf(v - bf2f(h));
  }
  for (int i = tid; i < CC * CC; i += 65536) wvbf[i] = f2bf(wv[i]);
}

// ---------------- kernel 1: x [B][C][N] f32 -> xT [B][N][C] bf16 ----------------
__global__ __launch_bounds__(256) void k_transpose(const float* __restrict__ x,
                                                   unsigned short* __restrict__ xT) {
  __shared__ float tile[64][65];
  const int b = blockIdx.z, c0 = blockIdx.y * 64, n0 = blockIdx.x * 64;
  const int t = threadIdx.x;
  {
    const int nq = (t & 15) * 4, cl0 = t >> 4;
    const float* xp = x + ((size_t)b * CC + c0) * NN + n0;
#pragma unroll
    for (int r = 0; r < 4; r++) {
      const int row = cl0 + r * 16;
      const f32x4 v = *reinterpret_cast<const f32x4*>(xp + (size_t)row * NN + nq);
      tile[row][nq] = v[0]; tile[row][nq + 1] = v[1];
      tile[row][nq + 2] = v[2]; tile[row][nq + 3] = v[3];
    }
  }
  __syncthreads();
  {
    const int cq = (t & 15) * 4, nl0 = t >> 4;
    unsigned short* xtp = xT + ((size_t)b * NN + n0) * CC + c0;
#pragma unroll
    for (int r = 0; r < 4; r++) {
      const int n = nl0 + r * 16;
      const ushort4 o = make_ushort4(f2bf(tile[cq][n]), f2bf(tile[cq + 1][n]),
                                     f2bf(tile[cq + 2][n]), f2bf(tile[cq + 3][n]));
      *reinterpret_cast<ushort4*>(xtp + (size_t)n * CC + cq) = o;
    }
  }
}

// ------------- kernel 2 (fused): Q/K projection (blocks 0..511) +
//                                 V projection (blocks 512..1535, n-tile 256) -------------
__global__ __launch_bounds__(256, 2) void k_proj(
    const unsigned short* __restrict__ xT,
    const unsigned short* __restrict__ wqhi, const unsigned short* __restrict__ wqlo,
    const unsigned short* __restrict__ wkhi, const unsigned short* __restrict__ wklo,
    const float* __restrict__ bq, const float* __restrict__ bk,
    const unsigned short* __restrict__ wvbf, const float* __restrict__ bv,
    unsigned short* __restrict__ qf, unsigned short* __restrict__ kf,
    unsigned short* __restrict__ vbf) {
  __shared__ float ksl[4][4][16];
  const int t = threadIdx.x, w = t >> 6, l = t & 63, lr = l & 15, g = l >> 4;

  if (blockIdx.x < 512) {
    const int b = blockIdx.x & 7;
    const int n0 = (blockIdx.x >> 3) * 64;
    const unsigned short* qhp = wqhi + (size_t)(w * 16 + lr) * CC + g * 8;
    const unsigned short* qlp = wqlo + (size_t)(w * 16 + lr) * CC + g * 8;
    const unsigned short* khp = wkhi + (size_t)(w * 16 + lr) * CC + g * 8;
    const unsigned short* klp = wklo + (size_t)(w * 16 + lr) * CC + g * 8;
    const unsigned short* xp = xT + ((size_t)b * NN + n0 + lr) * CC + g * 8;
    f32x4 qacc[4], kacc[4];
#pragma unroll
    for (int nf = 0; nf < 4; nf++) {
      qacc[nf] = f32x4{0.f, 0.f, 0.f, 0.f};
      kacc[nf] = f32x4{0.f, 0.f, 0.f, 0.f};
    }
    for (int cc = 0; cc < CC; cc += 32) {
      const bf16x8 qh8 = *reinterpret_cast<const bf16x8*>(qhp + cc);
      const bf16x8 ql8 = *reinterpret_cast<const bf16x8*>(qlp + cc);
      const bf16x8 kh8 = *reinterpret_cast<const bf16x8*>(khp + cc);
      const bf16x8 kl8 = *reinterpret_cast<const bf16x8*>(klp + cc);
      bf16x8 xb[4];
#pragma unroll
      for (int nf = 0; nf < 4; nf++)
        xb[nf] = *reinterpret_cast<const bf16x8*>(xp + (size_t)nf * 16 * CC + cc);
#pragma unroll
      for (int nf = 0; nf < 4; nf++) {
        qacc[nf] = __builtin_amdgcn_mfma_f32_16x16x32_bf16(qh8, xb[nf], qacc[nf], 0, 0, 0);
        qacc[nf] = __builtin_amdgcn_mfma_f32_16x16x32_bf16(ql8, xb[nf], qacc[nf], 0, 0, 0);
        kacc[nf] = __builtin_amdgcn_mfma_f32_16x16x32_bf16(kh8, xb[nf], kacc[nf], 0, 0, 0);
        kacc[nf] = __builtin_amdgcn_mfma_f32_16x16x32_bf16(kl8, xb[nf], kacc[nf], 0, 0, 0);
      }
    }
    float bqv[4], bkv[4];
#pragma unroll
    for (int r = 0; r < 4; r++) {
      bqv[r] = bq[w * 16 + g * 4 + r];
      bkv[r] = bk[w * 16 + g * 4 + r];
    }
    float kssp[4];
#pragma unroll
    for (int nf = 0; nf < 4; nf++) {
      float ks2 = 0.f;
      unsigned short qh[4], kh[4];
#pragma unroll
      for (int r = 0; r < 4; r++) {
        const float qv = (qacc[nf][r] + bqv[r]) * LOG2E;
        const float kv = kacc[nf][r] + bkv[r];
        qh[r] = f2h(qv); kh[r] = f2h(kv);
        ks2 += kv * kv;
      }
      kssp[nf] = ks2;
      const int n = n0 + nf * 16 + lr;
      const size_t base = ((size_t)b * NN + n) * MM + w * 16 + g * 4;
      *reinterpret_cast<ushort4*>(qf + base) = make_ushort4(qh[0], qh[1], qh[2], qh[3]);
      *reinterpret_cast<ushort4*>(kf + base) = make_ushort4(kh[0], kh[1], kh[2], kh[3]);
    }
#pragma unroll
    for (int nf = 0; nf < 4; nf++) {
      kssp[nf] += __shfl_xor(kssp[nf], 16);
      kssp[nf] += __shfl_xor(kssp[nf], 32);
    }
    if (l < 16) {
#pragma unroll
      for (int nf = 0; nf < 4; nf++) ksl[w][nf][lr] = kssp[nf];
    }
    __syncthreads();
    if (t < 64) {
      const int nf2 = t >> 4, lr2 = t & 15;
      float kn2 = ksl[0][nf2][lr2] + ksl[1][nf2][lr2] + ksl[2][nf2][lr2] + ksl[3][nf2][lr2];
#pragma unroll
      for (int d = 1; d < 64; d <<= 1) kn2 = fmaxf(kn2, __shfl_xor(kn2, d));
      if (t == 0) atomicMax(&g_kmax[b], __float_as_uint(kn2));
    }
  } else {
    const int blk = blockIdx.x - 512;                 // 0..1023
    const int b = blk >> 7, c0 = ((blk >> 4) & 7) * 64, n0 = (blk & 15) * 256;
    const int nbase = n0 + w * 64;
    f32x4 acc[4][4];
#pragma unroll
    for (int cf = 0; cf < 4; cf++)
#pragma unroll
      for (int nf = 0; nf < 4; nf++) acc[cf][nf] = f32x4{0.f, 0.f, 0.f, 0.f};
    for (int ks = 0; ks < 16; ks++) {
      const int kk = ks * 32 + g * 8;
      bf16x8 bfr[4];
#pragma unroll
      for (int nf = 0; nf < 4; nf++) {
        const int n = nbase + nf * 16 + lr;
        bfr[nf] = *reinterpret_cast<const bf16x8*>(xT + ((size_t)b * NN + n) * CC + kk);
      }
#pragma unroll
      for (int cf = 0; cf < 4; cf++) {
        const bf16x8 af = *reinterpret_cast<const bf16x8*>(
            wvbf + (size_t)(c0 + cf * 16 + lr) * CC + kk);
#pragma unroll
        for (int nf = 0; nf < 4; nf++)
          acc[cf][nf] = __builtin_amdgcn_mfma_f32_16x16x32_bf16(af, bfr[nf], acc[cf][nf], 0, 0, 0);
      }
    }
#pragma unroll
    for (int cf = 0; cf < 4; cf++) {
#pragma unroll
      for (int r = 0; r < 4; r++) {
        const int c = c0 + cf * 16 + g * 4 + r;
        const float bvv = bv[c];
#pragma unroll
        for (int nf = 0; nf < 4; nf++) {
          const int n = nbase + nf * 16 + lr;
          vbf[((size_t)b * CC + c) * NN + n] = f2bf(acc[cf][nf][r] + bvv);
        }
      }
    }
  }
}

// ---------------- kernel 3: attention + residual (bound-softmax) ----------------
// 8 waves (512 thr); block = 64 i x 512 c (no ch-split); grid 512; JT=64.
// Wave w: QK j-frag (w&3) x i-frag pair (w>>2); PV c-strip [64w, 64w+64).
// Region t (r7 skeleton): {V(t+1) prefetch, QK(t+1), K(t+2) prefetch,
//   exp2+cvt_pk+P-store(t+1)->buf^1, PV(t) from buf} -> lgkm-only barrier.
__global__ __launch_bounds__(512, 2) void k_attn(
    const unsigned short* __restrict__ qf, const unsigned short* __restrict__ kf,
    const unsigned short* __restrict__ vbf, const float* __restrict__ x,
    const float* __restrict__ gamma, float* __restrict__ out) {
  __shared__ unsigned short P_lds[2][64][64];  // 8 KB per buffer, XOR-swizzled
  __shared__ float l_red[8][2][16];
  const int b = blockIdx.x & 7;      // batch-pinned XCD swizzle
  const int i0 = (blockIdx.x >> 3) * 64;
  const int t = threadIdx.x, w = t >> 6, l = t & 63, lr = l & 15, g = l >> 4;
  const int jf = w & 3;              // QK j-frag
  const int ih = w >> 2;             // QK i-frag pair (0 or 1)
  const int wc = w * 64;             // PV channel strip

  // ---- Q fragments (fp16, log2e-scaled): i-frags 2ih, 2ih+1
  f16x8 qF[2][2];
#pragma unroll
  for (int qq = 0; qq < 2; qq++) {
    const int i = i0 + (ih * 2 + qq) * 16 + lr;
#pragma unroll
    for (int ks = 0; ks < 2; ks++)
      qF[qq][ks] = *reinterpret_cast<const f16x8*>(
          qf + ((size_t)b * NN + i) * MM + ks * 32 + g * 8);
  }
  // ---- mhat (log2 units): ||q~||*max||k||*(1+eps) - 44*log2e
  float mhat[2];
  {
    const float kroot = sqrtf(__uint_as_float(g_kmax[b])) * 1.001f;
#pragma unroll
    for (int qq = 0; qq < 2; qq++) {
      float ssq = 0.f;
#pragma unroll
      for (int ks = 0; ks < 2; ks++)
#pragma unroll
        for (int e = 0; e < 8; e++) {
          const float qv = (float)qF[qq][ks][e];
          ssq += qv * qv;
        }
      ssq += __shfl_xor(ssq, 16);
      ssq += __shfl_xor(ssq, 32);
      mhat[qq] = sqrtf(ssq) * kroot - 63.4786f;
    }
  }

  // K base: j = jb + jf*16 + lr
  const unsigned short* kp = kf + ((size_t)b * NN + jf * 16 + lr) * MM + g * 8;
  // V base: c = wc + cf*16 + lr, col j = jb + ks*32 + g*8
  const unsigned short* pv = vbf + ((size_t)b * CC + wc + lr) * NN + g * 8;

  f32x4 acc[4][4];  // [cf][i2]
#pragma unroll
  for (int cf = 0; cf < 4; cf++)
#pragma unroll
    for (int i2 = 0; i2 < 4; i2++) acc[cf][i2] = f32x4{0.f, 0.f, 0.f, 0.f};
  float lsum[2] = {0.f, 0.f};

  char* const pbase = (char*)&P_lds[0][0][0];
  const int rswz = (lr & 7) << 4;  // read-side XOR (row&7 == lr&7)
  int off_s[2];                    // P store byte offsets within one buffer
#pragma unroll
  for (int qq = 0; qq < 2; qq++) {
    const int row = (ih * 2 + qq) * 16 + lr;
    off_s[qq] = (row << 7) + ((jf * 32 + g * 8) ^ ((row & 7) << 4));
  }

  // ---- prologue: K(0); V(0); QK(0)->buf0; K(1); barrier
  f16x8 kA[2], kB[2];
#pragma unroll
  for (int ks = 0; ks < 2; ks++)
    kA[ks] = *reinterpret_cast<const f16x8*>(kp + (size_t)ks * 32);
  bf16x8 va[2][4], vb[2][4];  // [ks][cf]
#pragma unroll
  for (int ks = 0; ks < 2; ks++)
#pragma unroll
    for (int cf = 0; cf < 4; cf++)
      va[ks][cf] = *reinterpret_cast<const bf16x8*>(pv + (size_t)cf * (16 * NN) + ks * 32);
#pragma unroll
  for (int qq = 0; qq < 2; qq++) {
    f32x4 sa = __builtin_amdgcn_mfma_f32_16x16x32_f16(kA[0], qF[qq][0],
                                                      f32x4{0.f, 0.f, 0.f, 0.f}, 0, 0, 0);
    sa = __builtin_amdgcn_mfma_f32_16x16x32_f16(kA[1], qF[qq][1], sa, 0, 0, 0);
    const float p0 = __builtin_amdgcn_exp2f(sa[0] - mhat[qq]);
    const float p1 = __builtin_amdgcn_exp2f(sa[1] - mhat[qq]);
    const float p2 = __builtin_amdgcn_exp2f(sa[2] - mhat[qq]);
    const float p3 = __builtin_amdgcn_exp2f(sa[3] - mhat[qq]);
    lsum[qq] += (p0 + p1) + (p2 + p3);
    unsigned r01, r23;
    asm volatile("v_cvt_pk_bf16_f32 %0, %1, %2" : "=v"(r01) : "v"(p0), "v"(p1));
    asm volatile("v_cvt_pk_bf16_f32 %0, %1, %2" : "=v"(r23) : "v"(p2), "v"(p3));
    *reinterpret_cast<uint2*>(pbase + off_s[qq]) = make_uint2(r01, r23);
  }
#pragma unroll
  for (int ks = 0; ks < 2; ks++)
    kB[ks] = *reinterpret_cast<const f16x8*>(kp + (size_t)(64 * MM) + ks * 32);
  __builtin_amdgcn_sched_barrier(0);
  asm volatile("s_waitcnt lgkmcnt(0)" ::: "memory");
  __builtin_amdgcn_s_barrier();
  __builtin_amdgcn_sched_barrier(0);

  // ---- main regions (r7 order)
  auto region = [&](int jb, bf16x8 (&vcur)[2][4], bf16x8 (&vnext)[2][4],
                    f16x8 (&kuse)[2], f16x8 (&kpre)[2]) {
    const int par = (jb >> 6) & 1;
    const int j1 = (jb + 64) & (NN - 1);
    const int j2 = (jb + 128) & (NN - 1);
    // V(t+1) prefetch (window: whole region)
#pragma unroll
    for (int ks = 0; ks < 2; ks++)
#pragma unroll
      for (int cf = 0; cf < 4; cf++)
        vnext[ks][cf] = *reinterpret_cast<const bf16x8*>(
            pv + (size_t)cf * (16 * NN) + j1 + ks * 32);
    // QK(t+1)
    f32x4 sa[2];
#pragma unroll
    for (int qq = 0; qq < 2; qq++) {
      sa[qq] = __builtin_amdgcn_mfma_f32_16x16x32_f16(kuse[0], qF[qq][0],
                                                      f32x4{0.f, 0.f, 0.f, 0.f}, 0, 0, 0);
      sa[qq] = __builtin_amdgcn_mfma_f32_16x16x32_f16(kuse[1], qF[qq][1], sa[qq], 0, 0, 0);
    }
    // K(t+2) prefetch (stays in flight across the barrier)
#pragma unroll
    for (int ks = 0; ks < 2; ks++)
      kpre[ks] = *reinterpret_cast<const f16x8*>(kp + (size_t)j2 * MM + ks * 32);
    // exp2 + pack + store P(t+1) into buf par^1
    const bool vld = (jb + 64) < NN;
    char* const pw = pbase + ((par ^ 1) << 13);
#pragma unroll
    for (int qq = 0; qq < 2; qq++) {
      const float p0 = __builtin_amdgcn_exp2f(sa[qq][0] - mhat[qq]);
      const float p1 = __builtin_amdgcn_exp2f(sa[qq][1] - mhat[qq]);
      const float p2 = __builtin_amdgcn_exp2f(sa[qq][2] - mhat[qq]);
      const float p3 = __builtin_amdgcn_exp2f(sa[qq][3] - mhat[qq]);
      if (vld) lsum[qq] += (p0 + p1) + (p2 + p3);
      unsigned r01, r23;
      asm volatile("v_cvt_pk_bf16_f32 %0, %1, %2" : "=v"(r01) : "v"(p0), "v"(p1));
      asm volatile("v_cvt_pk_bf16_f32 %0, %1, %2" : "=v"(r23) : "v"(p2), "v"(p3));
      *reinterpret_cast<uint2*>(pw + off_s[qq]) = make_uint2(r01, r23);
    }
    // PV(t) from buf par
    char* const pr = pbase + (par << 13);
    __builtin_amdgcn_s_setprio(1);
#pragma unroll
    for (int ks = 0; ks < 2; ks++) {
#pragma unroll
      for (int i2 = 0; i2 < 4; i2++) {
        const int row = i2 * 16 + lr;
        const bf16x8 pf = *reinterpret_cast<const bf16x8*>(
            pr + (row << 7) + ((ks * 64 + g * 16) ^ rswz));
#pragma unroll
        for (int cf = 0; cf < 4; cf++)
          acc[cf][i2] = __builtin_amdgcn_mfma_f32_16x16x32_bf16(
              vcur[ks][cf], pf, acc[cf][i2], 0, 0, 0);
      }
    }
    __builtin_amdgcn_s_setprio(0);
    // barrier: drain LDS only; global prefetches stay in flight
    __builtin_amdgcn_sched_barrier(0);
    asm volatile("s_waitcnt lgkmcnt(0)" ::: "memory");
    __builtin_amdgcn_s_barrier();
    __builtin_amdgcn_sched_barrier(0);
  };

  for (int tt = 0; tt < 32; tt++) {
    region(tt * 128, va, vb, kB, kA);
    region(tt * 128 + 64, vb, va, kA, kB);
  }

  // ---- l reduction: over g (shfl), publish, sum across the 4 j-frag waves
#pragma unroll
  for (int qq = 0; qq < 2; qq++) {
    lsum[qq] += __shfl_xor(lsum[qq], 16);
    lsum[qq] += __shfl_xor(lsum[qq], 32);
  }
  if (l < 16) {
#pragma unroll
    for (int qq = 0; qq < 2; qq++) l_red[w][qq][lr] = lsum[qq];
  }
  __syncthreads();
  const float gm = gamma[0];
  float inv[4];
#pragma unroll
  for (int i2 = 0; i2 < 4; i2++) {
    const int ihh = i2 >> 1, qq = i2 & 1;
    inv[i2] = gm / (l_red[ihh * 4 + 0][qq][lr] + l_red[ihh * 4 + 1][qq][lr] +
                    l_red[ihh * 4 + 2][qq][lr] + l_red[ihh * 4 + 3][qq][lr]);
  }

  // ---- epilogue: out = gamma * O / l + x
#pragma unroll
  for (int cf = 0; cf < 4; cf++) {
#pragma unroll
    for (int r = 0; r < 4; r++) {
      const int c = wc + cf * 16 + g * 4 + r;
      const size_t rowo = ((size_t)b * CC + c) * NN;
#pragma unroll
      for (int i2 = 0; i2 < 4; i2++) {
        const int i = i0 + i2 * 16 + lr;
        out[rowo + i] = acc[cf][i2][r] * inv[i2] + x[rowo + i];
      }
    }
  }
}

extern "C" void kernel_launch(void* const* d_in, const int* in_sizes, int n_in,
                              void* d_out, int out_size, void* d_ws, size_t ws_size,
                              hipStream_t stream) {
  const float* x = (const float*)d_in[0];
  const float* wq = (const float*)d_in[1];
  const float* bq = (const float*)d_in[2];
  const float* wk = (const float*)d_in[3];
  const float* bk = (const float*)d_in[4];
  const float* wv = (const float*)d_in[5];
  const float* bv = (const float*)d_in[6];
  const float* gamma = (const float*)d_in[7];
  float* out = (float*)d_out;

  char* ws = (char*)d_ws;
  unsigned short* xT = (unsigned short*)(ws);                 // 32 MB [B][N][C] bf16
  unsigned short* vbf = (unsigned short*)(ws + 33554432);     // 32 MB [B][C][N] bf16
  unsigned short* qfp = (unsigned short*)(ws + 67108864);     // 4 MB  [B][N][64] fp16 (log2e-scaled)
  unsigned short* kfp = (unsigned short*)(ws + 71303168);     // 4 MB  [B][N][64] fp16
  unsigned short* wqhi = (unsigned short*)(ws + 75497472);    // 64 KB
  unsigned short* wqlo = (unsigned short*)(ws + 75563008);    // 64 KB
  unsigned short* wkhi = (unsigned short*)(ws + 75628544);    // 64 KB
  unsigned short* wklo = (unsigned short*)(ws + 75694080);    // 64 KB
  unsigned short* wvbf = (unsigned short*)(ws + 75759616);    // 512 KB

  k_wconv<<<256, 256, 0, stream>>>(wq, wk, wv, wqhi, wqlo, wkhi, wklo, wvbf);
  k_transpose<<<dim3(64, 8, 8), 256, 0, stream>>>(x, xT);
  k_proj<<<1536, 256, 0, stream>>>(xT, wqhi, wqlo, wkhi, wklo, bq, bk, wvbf, bv,
                                   qfp, kfp, vbf);
  k_attn<<<dim3(512), 512, 0, stream>>>(qfp, kfp, vbf, x, gamma, out);
}

// Round 12
// 327.892 us; speedup vs baseline: 1.2839x; 1.2839x over previous
//
#include <hip/hip_runtime.h>
#include <hip/hip_bf16.h>

// PAM (position attention): B=8, C=512, mid=64, N=64*64=4096.
// Round 12: k_attn rebuilt on 32x32x16 MFMA fragments.
//  - One block = 128 i x FULL 512 c (no ch-split dup), grid 256 (1/CU).
//  - Swapped QK 32x32 (A=K,B=Q): D = P[j32][i32], i=lane&31 (m74/m101 layout).
//  - P exchange through u32 [jpair][i] LDS: conflict-free b32 both sides;
//    P's B-frag and V's A-frag use the SAME k-element formula (HW-perm cancels).
//  - PV 32x32: wave owns 64c x 128i (acc 128 regs); V read once per region.
//  - r7's race-free region order + lgkm-only barrier + bound-softmax kept.
// Aux (wconv/transpose/fused proj) unchanged from r11.

#define BB 8
#define CC 512
#define MM 64
#define NN 4096
#define LOG2E 1.4426950408889634f

typedef __attribute__((ext_vector_type(8))) short bf16x8;
typedef __attribute__((ext_vector_type(8))) _Float16 f16x8;
typedef __attribute__((ext_vector_type(4))) float f32x4;
typedef __attribute__((ext_vector_type(16))) float f32x16;

__device__ unsigned g_kmax[BB];  // per-batch max ||k||^2 (uint-ordered f32)

__device__ __forceinline__ unsigned short f2bf(float f) {
  union { float f; unsigned u; } v; v.f = f;
  unsigned r = v.u + 0x7fffu + ((v.u >> 16) & 1u);  // RNE
  return (unsigned short)(r >> 16);
}
__device__ __forceinline__ float bf2f(unsigned short h) {
  union { unsigned u; float f; } v; v.u = ((unsigned)h) << 16;
  return v.f;
}
__device__ __forceinline__ unsigned short f2h(float f) {
  union { _Float16 h; unsigned short u; } v; v.h = (_Float16)f;
  return v.u;
}

#define PC_BARRIER()                                        \
  do {                                                      \
    __builtin_amdgcn_sched_barrier(0);                      \
    asm volatile("s_waitcnt lgkmcnt(0)" ::: "memory");      \
    __builtin_amdgcn_s_barrier();                           \
    __builtin_amdgcn_sched_barrier(0);                      \
  } while (0)

// ------------- kernel 0: weight pre-conversion + g_kmax init -------------
__global__ __launch_bounds__(256) void k_wconv(
    const float* __restrict__ wq, const float* __restrict__ wk,
    const float* __restrict__ wv,
    unsigned short* __restrict__ wqhi, unsigned short* __restrict__ wqlo,
    unsigned short* __restrict__ wkhi, unsigned short* __restrict__ wklo,
    unsigned short* __restrict__ wvbf) {
  const int tid = blockIdx.x * 256 + threadIdx.x;
  if (tid < BB) g_kmax[tid] = 0u;
  if (tid < MM * CC) {
    float v = wq[tid];
    unsigned short h = f2bf(v);
    wqhi[tid] = h; wqlo[tid] = f2bf(v - bf2f(h));
    v = wk[tid]; h = f2bf(v);
    wkhi[tid] = h; wklo[tid] = f2bf(v - bf2f(h));
  }
  for (int i = tid; i < CC * CC; i += 65536) wvbf[i] = f2bf(wv[i]);
}

// ---------------- kernel 1: x [B][C][N] f32 -> xT [B][N][C] bf16 ----------------
__global__ __launch_bounds__(256) void k_transpose(const float* __restrict__ x,
                                                   unsigned short* __restrict__ xT) {
  __shared__ float tile[64][65];
  const int b = blockIdx.z, c0 = blockIdx.y * 64, n0 = blockIdx.x * 64;
  const int t = threadIdx.x;
  {
    const int nq = (t & 15) * 4, cl0 = t >> 4;
    const float* xp = x + ((size_t)b * CC + c0) * NN + n0;
#pragma unroll
    for (int r = 0; r < 4; r++) {
      const int row = cl0 + r * 16;
      const f32x4 v = *reinterpret_cast<const f32x4*>(xp + (size_t)row * NN + nq);
      tile[row][nq] = v[0]; tile[row][nq + 1] = v[1];
      tile[row][nq + 2] = v[2]; tile[row][nq + 3] = v[3];
    }
  }
  __syncthreads();
  {
    const int cq = (t & 15) * 4, nl0 = t >> 4;
    unsigned short* xtp = xT + ((size_t)b * NN + n0) * CC + c0;
#pragma unroll
    for (int r = 0; r < 4; r++) {
      const int n = nl0 + r * 16;
      const ushort4 o = make_ushort4(f2bf(tile[cq][n]), f2bf(tile[cq + 1][n]),
                                     f2bf(tile[cq + 2][n]), f2bf(tile[cq + 3][n]));
      *reinterpret_cast<ushort4*>(xtp + (size_t)n * CC + cq) = o;
    }
  }
}

// ------------- kernel 2 (fused): Q/K projection (blocks 0..511) +
//                                 V projection (blocks 512..1535, n-tile 256) -------------
__global__ __launch_bounds__(256, 2) void k_proj(
    const unsigned short* __restrict__ xT,
    const unsigned short* __restrict__ wqhi, const unsigned short* __restrict__ wqlo,
    const unsigned short* __restrict__ wkhi, const unsigned short* __restrict__ wklo,
    const float* __restrict__ bq, const float* __restrict__ bk,
    const unsigned short* __restrict__ wvbf, const float* __restrict__ bv,
    unsigned short* __restrict__ qf, unsigned short* __restrict__ kf,
    unsigned short* __restrict__ vbf) {
  __shared__ float ksl[4][4][16];
  const int t = threadIdx.x, w = t >> 6, l = t & 63, lr = l & 15, g = l >> 4;

  if (blockIdx.x < 512) {
    const int b = blockIdx.x & 7;
    const int n0 = (blockIdx.x >> 3) * 64;
    const unsigned short* qhp = wqhi + (size_t)(w * 16 + lr) * CC + g * 8;
    const unsigned short* qlp = wqlo + (size_t)(w * 16 + lr) * CC + g * 8;
    const unsigned short* khp = wkhi + (size_t)(w * 16 + lr) * CC + g * 8;
    const unsigned short* klp = wklo + (size_t)(w * 16 + lr) * CC + g * 8;
    const unsigned short* xp = xT + ((size_t)b * NN + n0 + lr) * CC + g * 8;
    f32x4 qacc[4], kacc[4];
#pragma unroll
    for (int nf = 0; nf < 4; nf++) {
      qacc[nf] = f32x4{0.f, 0.f, 0.f, 0.f};
      kacc[nf] = f32x4{0.f, 0.f, 0.f, 0.f};
    }
    for (int cc = 0; cc < CC; cc += 32) {
      const bf16x8 qh8 = *reinterpret_cast<const bf16x8*>(qhp + cc);
      const bf16x8 ql8 = *reinterpret_cast<const bf16x8*>(qlp + cc);
      const bf16x8 kh8 = *reinterpret_cast<const bf16x8*>(khp + cc);
      const bf16x8 kl8 = *reinterpret_cast<const bf16x8*>(klp + cc);
      bf16x8 xb[4];
#pragma unroll
      for (int nf = 0; nf < 4; nf++)
        xb[nf] = *reinterpret_cast<const bf16x8*>(xp + (size_t)nf * 16 * CC + cc);
#pragma unroll
      for (int nf = 0; nf < 4; nf++) {
        qacc[nf] = __builtin_amdgcn_mfma_f32_16x16x32_bf16(qh8, xb[nf], qacc[nf], 0, 0, 0);
        qacc[nf] = __builtin_amdgcn_mfma_f32_16x16x32_bf16(ql8, xb[nf], qacc[nf], 0, 0, 0);
        kacc[nf] = __builtin_amdgcn_mfma_f32_16x16x32_bf16(kh8, xb[nf], kacc[nf], 0, 0, 0);
        kacc[nf] = __builtin_amdgcn_mfma_f32_16x16x32_bf16(kl8, xb[nf], kacc[nf], 0, 0, 0);
      }
    }
    float bqv[4], bkv[4];
#pragma unroll
    for (int r = 0; r < 4; r++) {
      bqv[r] = bq[w * 16 + g * 4 + r];
      bkv[r] = bk[w * 16 + g * 4 + r];
    }
    float kssp[4];
#pragma unroll
    for (int nf = 0; nf < 4; nf++) {
      float ks2 = 0.f;
      unsigned short qh[4], kh[4];
#pragma unroll
      for (int r = 0; r < 4; r++) {
        const float qv = (qacc[nf][r] + bqv[r]) * LOG2E;
        const float kv = kacc[nf][r] + bkv[r];
        qh[r] = f2h(qv); kh[r] = f2h(kv);
        ks2 += kv * kv;
      }
      kssp[nf] = ks2;
      const int n = n0 + nf * 16 + lr;
      const size_t base = ((size_t)b * NN + n) * MM + w * 16 + g * 4;
      *reinterpret_cast<ushort4*>(qf + base) = make_ushort4(qh[0], qh[1], qh[2], qh[3]);
      *reinterpret_cast<ushort4*>(kf + base) = make_ushort4(kh[0], kh[1], kh[2], kh[3]);
    }
#pragma unroll
    for (int nf = 0; nf < 4; nf++) {
      kssp[nf] += __shfl_xor(kssp[nf], 16);
      kssp[nf] += __shfl_xor(kssp[nf], 32);
    }
    if (l < 16) {
#pragma unroll
      for (int nf = 0; nf < 4; nf++) ksl[w][nf][lr] = kssp[nf];
    }
    __syncthreads();
    if (t < 64) {
      const int nf2 = t >> 4, lr2 = t & 15;
      float kn2 = ksl[0][nf2][lr2] + ksl[1][nf2][lr2] + ksl[2][nf2][lr2] + ksl[3][nf2][lr2];
#pragma unroll
      for (int d = 1; d < 64; d <<= 1) kn2 = fmaxf(kn2, __shfl_xor(kn2, d));
      if (t == 0) atomicMax(&g_kmax[b], __float_as_uint(kn2));
    }
  } else {
    const int blk = blockIdx.x - 512;                 // 0..1023
    const int b = blk >> 7, c0 = ((blk >> 4) & 7) * 64, n0 = (blk & 15) * 256;
    const int nbase = n0 + w * 64;
    f32x4 acc[4][4];
#pragma unroll
    for (int cf = 0; cf < 4; cf++)
#pragma unroll
      for (int nf = 0; nf < 4; nf++) acc[cf][nf] = f32x4{0.f, 0.f, 0.f, 0.f};
    for (int ks = 0; ks < 16; ks++) {
      const int kk = ks * 32 + g * 8;
      bf16x8 bfr[4];
#pragma unroll
      for (int nf = 0; nf < 4; nf++) {
        const int n = nbase + nf * 16 + lr;
        bfr[nf] = *reinterpret_cast<const bf16x8*>(xT + ((size_t)b * NN + n) * CC + kk);
      }
#pragma unroll
      for (int cf = 0; cf < 4; cf++) {
        const bf16x8 af = *reinterpret_cast<const bf16x8*>(
            wvbf + (size_t)(c0 + cf * 16 + lr) * CC + kk);
#pragma unroll
        for (int nf = 0; nf < 4; nf++)
          acc[cf][nf] = __builtin_amdgcn_mfma_f32_16x16x32_bf16(af, bfr[nf], acc[cf][nf], 0, 0, 0);
      }
    }
#pragma unroll
    for (int cf = 0; cf < 4; cf++) {
#pragma unroll
      for (int r = 0; r < 4; r++) {
        const int c = c0 + cf * 16 + g * 4 + r;
        const float bvv = bv[c];
#pragma unroll
        for (int nf = 0; nf < 4; nf++) {
          const int n = nbase + nf * 16 + lr;
          vbf[((size_t)b * CC + c) * NN + n] = f2bf(acc[cf][nf][r] + bvv);
        }
      }
    }
  }
}

// ---------------- kernel 3: attention + residual (32x32 frags, bound-softmax) ----
// 8 waves (512 thr); block = 128 i x 512 c; grid 256 (1 block/CU); JT=64.
// QK role: wave w -> (jf = w&1, ifq = w>>1): S^T[j 32][i 32] via 4x mfma_32x32x16_f16.
//   D: col i = lane&31, row j' = (r&3)+8*(r>>2)+4*(lane>>5).
// P exchange: cvt_pk pairs (j'=2s,2s+1) -> u32 LDS [jpair 32][i 128] (conflict-free
//   b32 both sides). PV B-frag word wd (lane l) = Pg[ks*8 + (l>>5)*4 + wd][i] ->
//   element pair (2wd,2wd+1) = j = ks*16 + (l>>5)*8 + {2wd,2wd+1}, exactly matching
//   V's A-frag element map (HW k-permutation cancels).
// PV role: wave w owns c-strip [64w, 64w+64) x ALL 128 i; acc[2][4] f32x16.
// Region t: {V(t), QK(t+1), K(t+2) pre, exp2+pack, P(t+1)->buf^1, PV(t)<-buf,
//            lgkm-only barrier}  (r7's race-free order).
__global__ __launch_bounds__(512, 2) void k_attn(
    const unsigned short* __restrict__ qf, const unsigned short* __restrict__ kf,
    const unsigned short* __restrict__ vbf, const float* __restrict__ x,
    const float* __restrict__ gamma, float* __restrict__ out) {
  __shared__ unsigned Pg[2][32][128];   // [parity][jpair][i] u32 (bf16 pair)
  __shared__ float l_red[2][4][32];
  const int b = blockIdx.x & 7;         // batch-pinned XCD swizzle
  const int i0 = (blockIdx.x >> 3) * 128;
  const int t = threadIdx.x, w = t >> 6, l = t & 63;
  const int l31 = l & 31, h = l >> 5, h4 = h * 4, h8 = h * 8;
  const int jf = w & 1;                 // QK j-half of the 64-tile
  const int ifq = w >> 1;               // QK i-block (0..3)
  const int wc = w * 64;                // PV channel strip

  // ---- Q B-frags (fp16, log2e-scaled): i = i0 + ifq*32 + l31, k = kf*16 + h8 + e
  f16x8 qF[4];
#pragma unroll
  for (int kfi = 0; kfi < 4; kfi++)
    qF[kfi] = *reinterpret_cast<const f16x8*>(
        qf + ((size_t)b * NN + i0 + ifq * 32 + l31) * MM + kfi * 16 + h8);
  // ---- mhat (log2 units), one scalar per lane (its i column)
  float mhat;
  {
    float ssq = 0.f;
#pragma unroll
    for (int kfi = 0; kfi < 4; kfi++)
#pragma unroll
      for (int e = 0; e < 8; e++) {
        const float qv = (float)qF[kfi][e];
        ssq += qv * qv;
      }
    ssq += __shfl_xor(ssq, 32);
    mhat = sqrtf(ssq) * sqrtf(__uint_as_float(g_kmax[b])) * 1.001f - 63.4786f;
  }

  // K A-frag base: row j = jb + jf*32 + l31, col kf*16 + h8
  const unsigned short* kp = kf + ((size_t)b * NN + jf * 32 + l31) * MM + h8;
  // V A-frag base: row c = wc + cf*32 + l31, col jb + ks*16 + h8
  const unsigned short* pvp = vbf + ((size_t)b * CC + wc + l31) * NN + h8;

  f32x16 acc[2][4];  // [cf][if_]
#pragma unroll
  for (int cf = 0; cf < 2; cf++)
#pragma unroll
    for (int f = 0; f < 4; f++)
      acc[cf][f] = f32x16{0.f, 0.f, 0.f, 0.f, 0.f, 0.f, 0.f, 0.f,
                          0.f, 0.f, 0.f, 0.f, 0.f, 0.f, 0.f, 0.f};
  float lsum = 0.f;

  // ---- QK helper: sa(tile) -> exp2 -> pack -> store into Pg[par]
  unsigned* const pg0 = &Pg[0][0][0];
  auto produce = [&](const f16x8 (&kk)[4], int par, bool addl) {
    f32x16 sa = f32x16{0.f, 0.f, 0.f, 0.f, 0.f, 0.f, 0.f, 0.f,
                       0.f, 0.f, 0.f, 0.f, 0.f, 0.f, 0.f, 0.f};
#pragma unroll
    for (int kfi = 0; kfi < 4; kfi++)
      sa = __builtin_amdgcn_mfma_f32_32x32x16_f16(kk[kfi], qF[kfi], sa, 0, 0, 0);
    float p[16];
#pragma unroll
    for (int r = 0; r < 16; r++) p[r] = __builtin_amdgcn_exp2f(sa[r] - mhat);
    if (addl) {
      float ps = 0.f;
#pragma unroll
      for (int r = 0; r < 16; r++) ps += p[r];
      lsum += ps;
    }
    unsigned* pw = pg0 + par * (32 * 128);
#pragma unroll
    for (int s = 0; s < 8; s++) {
      unsigned u;
      asm volatile("v_cvt_pk_bf16_f32 %0, %1, %2" : "=v"(u) : "v"(p[2 * s]), "v"(p[2 * s + 1]));
      // jpair = jf*16 + (s&1) + 4*(s>>1) + 2h   (from D row j' = (r&3)+8(r>>2)+4h)
      pw[(jf * 16 + (s & 1) + 4 * (s >> 1) + 2 * h) * 128 + ifq * 32 + l31] = u;
    }
  };

  // ---- prologue: K(0), K(1); P(0)->buf0; barrier
  f16x8 kA[4], kB[4];
#pragma unroll
  for (int kfi = 0; kfi < 4; kfi++) {
    kA[kfi] = *reinterpret_cast<const f16x8*>(kp + (size_t)kfi * 16);
    kB[kfi] = *reinterpret_cast<const f16x8*>(kp + (size_t)64 * MM + kfi * 16);
  }
  produce(kA, 0, true);
  PC_BARRIER();

  // ---- main regions
  auto region = [&](int tt, f16x8 (&kuse)[4], f16x8 (&kpre)[4]) {
    const int jb = tt * 64;
    const int j2 = (jb + 128) & (NN - 1);
    const int par = tt & 1;
    // V(t) — consumed in PV below (window: QK+exp+pack+stores)
    bf16x8 vr[2][4];  // [cf][ks]
#pragma unroll
    for (int cf = 0; cf < 2; cf++)
#pragma unroll
      for (int ks = 0; ks < 4; ks++)
        vr[cf][ks] = *reinterpret_cast<const bf16x8*>(
            pvp + (size_t)cf * (32 * NN) + jb + ks * 16);
    // K(t+2) prefetch (rides through the barrier)
#pragma unroll
    for (int kfi = 0; kfi < 4; kfi++)
      kpre[kfi] = *reinterpret_cast<const f16x8*>(kp + (size_t)j2 * MM + kfi * 16);
    // QK(t+1) -> exp -> pack -> store into buf[par^1]
    produce(kuse, par ^ 1, jb + 64 < NN);
    // PV(t) from buf[par]
    const unsigned* pr = pg0 + par * (32 * 128);
    __builtin_amdgcn_s_setprio(1);
#pragma unroll
    for (int ks = 0; ks < 4; ks++) {
#pragma unroll
      for (int f = 0; f < 4; f++) {
        uint4 bw;
        bw.x = pr[(ks * 8 + h4 + 0) * 128 + f * 32 + l31];
        bw.y = pr[(ks * 8 + h4 + 1) * 128 + f * 32 + l31];
        bw.z = pr[(ks * 8 + h4 + 2) * 128 + f * 32 + l31];
        bw.w = pr[(ks * 8 + h4 + 3) * 128 + f * 32 + l31];
        const bf16x8 B = *reinterpret_cast<const bf16x8*>(&bw);
        acc[0][f] = __builtin_amdgcn_mfma_f32_32x32x16_bf16(vr[0][ks], B, acc[0][f], 0, 0, 0);
        acc[1][f] = __builtin_amdgcn_mfma_f32_32x32x16_bf16(vr[1][ks], B, acc[1][f], 0, 0, 0);
      }
    }
    __builtin_amdgcn_s_setprio(0);
    PC_BARRIER();
  };

  for (int tt = 0; tt < 32; tt++) {
    region(2 * tt, kB, kA);
    region(2 * tt + 1, kA, kB);
  }

  // ---- l reduction: lanes l,l+32 share i -> fold, publish per (jf, ifq)
  lsum += __shfl_xor(lsum, 32);
  if (l < 32) l_red[jf][ifq][l] = lsum;
  __syncthreads();
  const float gm = gamma[0];
  float inv[4];
#pragma unroll
  for (int f = 0; f < 4; f++)
    inv[f] = gm / (l_red[0][f][l31] + l_red[1][f][l31]);

  // ---- epilogue: out = gamma * O / l + x
  // D layout: col i = l31 (+ if_*32), row c = (r&3)+8*(r>>2)+4h (+ cf*32 + wc)
#pragma unroll
  for (int cf = 0; cf < 2; cf++) {
#pragma unroll
    for (int f = 0; f < 4; f++) {
#pragma unroll
      for (int r = 0; r < 16; r++) {
        const int c = wc + cf * 32 + (r & 3) + 8 * (r >> 2) + 4 * h;
        const int i = i0 + f * 32 + l31;
        const size_t o = ((size_t)b * CC + c) * NN + i;
        out[o] = acc[cf][f][r] * inv[f] + x[o];
      }
    }
  }
}

extern "C" void kernel_launch(void* const* d_in, const int* in_sizes, int n_in,
                              void* d_out, int out_size, void* d_ws, size_t ws_size,
                              hipStream_t stream) {
  const float* x = (const float*)d_in[0];
  const float* wq = (const float*)d_in[1];
  const float* bq = (const float*)d_in[2];
  const float* wk = (const float*)d_in[3];
  const float* bk = (const float*)d_in[4];
  const float* wv = (const float*)d_in[5];
  const float* bv = (const float*)d_in[6];
  const float* gamma = (const float*)d_in[7];
  float* out = (float*)d_out;

  char* ws = (char*)d_ws;
  unsigned short* xT = (unsigned short*)(ws);                 // 32 MB [B][N][C] bf16
  unsigned short* vbf = (unsigned short*)(ws + 33554432);     // 32 MB [B][C][N] bf16
  unsigned short* qfp = (unsigned short*)(ws + 67108864);     // 4 MB  [B][N][64] fp16 (log2e-scaled)
  unsigned short* kfp = (unsigned short*)(ws + 71303168);     // 4 MB  [B][N][64] fp16
  unsigned short* wqhi = (unsigned short*)(ws + 75497472);    // 64 KB
  unsigned short* wqlo = (unsigned short*)(ws + 75563008);    // 64 KB
  unsigned short* wkhi = (unsigned short*)(ws + 75628544);    // 64 KB
  unsigned short* wklo = (unsigned short*)(ws + 75694080);    // 64 KB
  unsigned short* wvbf = (unsigned short*)(ws + 75759616);    // 512 KB

  k_wconv<<<256, 256, 0, stream>>>(wq, wk, wv, wqhi, wqlo, wkhi, wklo, wvbf);
  k_transpose<<<dim3(64, 8, 8), 256, 0, stream>>>(x, xT);
  k_proj<<<1536, 256, 0, stream>>>(xT, wqhi, wqlo, wkhi, wklo, bq, bk, wvbf, bv,
                                   qfp, kfp, vbf);
  k_attn<<<dim3(256), 512, 0, stream>>>(qfp, kfp, vbf, x, gamma, out);
}